// Round 7
// baseline (151.788 us; speedup 1.0000x reference)
//
#include <hip/hip_runtime.h>
#include <hip/hip_bf16.h>
#include <stdint.h>

// Single attention head. B=4, T=2048, C=1024, H=64. FP32 in/out (proven).
// Outputs concat fp32: out[B,T,H], k[B,T,H], v[B,T,H]. scale = 1/32.
//
// R18 = R17 with the flag-zeroing bug fixed (R17 FAILED absmax 3.97: prep_wb
// zeroed flags with threadIdx.x < 512 under blockDim=256, so flags[256..511]
// (b>=2) stayed poisoned and the second-arriver branch never fired -> out for
// batches 2,3 never written). Fix: block 0 zeroes tid and tid+256.
// R16/R17 design: R15 (qkv 32-row Wb-reuse, proven 106.9us) + attn z-split:
//  - attn: grid (128,4,2). Block z covers kt = z*4+wave (stride 8): critical
//    wave path 8 -> 4 tiles; 1024 blocks -> ~4/CU for latency hiding. Each
//    block writes its partial O (4KB) + l to ws, then threadfence +
//    device-scope atomicAdd on a per-(qt,b) flag; the SECOND arriver combines
//    (own partial still in regs), normalizes, writes out. No extra launch.
//    fp add is commutative -> result deterministic regardless of winner.
// ws: [0) Wb 384KB; [1MB) qb; [2MB) kb; [3MB) vT; [4MB) flags 2KB;
//     [4MB+8KB) Lpart 64KB; [4MB+128KB) Opart 4MB.

#define NB 4
#define TT 2048
#define CC 1024
#define HH 64
#define NKV (NB * TT * HH)

typedef __attribute__((ext_vector_type(8))) short short8; // 8 bf16 = 4 VGPRs
typedef __attribute__((ext_vector_type(4))) float f32x4;  // MFMA C/D

__device__ __forceinline__ unsigned short f2bf(float f) {
    union { float f; unsigned int i; } v;
    v.f = f;
    unsigned int r = v.i + 0x7fffu + ((v.i >> 16) & 1u); // RNE
    return (unsigned short)(r >> 16);
}
// packed RNE f32x2 -> bf16x2 (v_cvt_pk_bf16_f32 on gfx950)
__device__ __forceinline__ unsigned int pkbf2(float a, float b) {
    __hip_bfloat162 h = __float22bfloat162_rn(make_float2(a, b));
    union { __hip_bfloat162 h; unsigned int u; } c;
    c.h = h;
    return c.u;
}

// ---------------------------------------------------------------------------
// prep_wb (R9/R10-proven) + flag zeroing (FIXED: covers all 512 entries):
// Wb[((s*32+kk)*64 + l)*8 + j] =
// W_m[k = 32kk + (l>>4)*8 + j][h = (s&3)*16 + (l&15)], m = s>>2.
// ---------------------------------------------------------------------------
__global__ __launch_bounds__(256) void prep_wb(const float* __restrict__ Wq,
                                               const float* __restrict__ Wk,
                                               const float* __restrict__ Wv,
                                               unsigned short* __restrict__ Wb,
                                               unsigned int* __restrict__ flags) {
    if (blockIdx.x == 0) {
        flags[threadIdx.x]       = 0u;
        flags[threadIdx.x + 256] = 0u;
    }
    int gid = blockIdx.x * 256 + threadIdx.x; // 0 .. 196607
    int j  = gid & 7;
    int l  = (gid >> 3) & 63;
    int kk = (gid >> 9) & 31;
    int s  = gid >> 14;
    int k  = kk * 32 + (l >> 4) * 8 + j;
    int h  = (s & 3) * 16 + (l & 15);
    const float* W = (s >> 2) == 0 ? Wq : (s >> 2) == 1 ? Wk : Wv;
    Wb[gid] = f2bf(W[(size_t)k * HH + h]);
}

// ---------------------------------------------------------------------------
// qkv_mfma v2 (R15-proven): 256 blocks x 512 threads, 32 rows/block, 8 waves.
// Wave w: row-tile rt = w>>2, frag set fw = w&3. x staged to LDS bf16,
// 32x1024, XOR-swizzled on 8B units: phys_u = u ^ ((row&7)<<1).
// ---------------------------------------------------------------------------
#define SC2F 0.0450842200113808f // (1/32)*log2(e)

__global__ __launch_bounds__(512) void qkv_mfma(const float* __restrict__ x,
                                                const unsigned short* __restrict__ Wb,
                                                float* __restrict__ out,
                                                unsigned short* __restrict__ qb,
                                                unsigned short* __restrict__ kb,
                                                unsigned short* __restrict__ vT) {
    __shared__ __align__(16) unsigned short xs[32 * 1024]; // 64KB exactly
    const int t    = threadIdx.x;
    const int wave = t >> 6, lane = t & 63;
    const int n    = lane & 15, quad = lane >> 4;
    const int fw   = wave & 3, rt = wave >> 2;
    const int row0 = blockIdx.x * 32;
    const int b    = row0 >> 11;

    // stage x tile (32 rows x 1024) fp32 -> bf16, swizzled write
    {
        const int tr = t >> 8, tc = t & 255; // tc = 8B unit within row
#pragma unroll 8
        for (int it = 0; it < 16; ++it) {
            const int i = it * 2 + tr;
            float4 f = *(const float4*)(x + (size_t)(row0 + i) * CC + 4 * tc);
            uint2 u;
            u.x = pkbf2(f.x, f.y);
            u.y = pkbf2(f.z, f.w);
            *(uint2*)&xs[i * 1024 + ((tc ^ ((i & 7) << 1)) << 2)] = u;
        }
    }
    __syncthreads();

    f32x4 acc0 = (f32x4){0.f, 0.f, 0.f, 0.f};
    f32x4 acc1 = acc0, acc2 = acc0;

    const unsigned short* wp = Wb + (size_t)lane * 8;
    const size_t fs = (size_t)32 * 64 * 8; // frag-s stride
    const int arow = (rt * 16 + n) * 1024;
    const int axor = (n & 7) << 1;

#pragma unroll 4
    for (int kk = 0; kk < 32; ++kk) {
        short8 a = *(const short8*)&xs[arow + (((kk * 8 + quad * 2) ^ axor) << 2)];
        const unsigned short* wk_ = wp + (size_t)kk * 512;
        short8 b0 = *(const short8*)(wk_ + (size_t)(fw)     * fs);
        short8 b1 = *(const short8*)(wk_ + (size_t)(fw + 4) * fs);
        short8 b2 = *(const short8*)(wk_ + (size_t)(fw + 8) * fs);
        acc0 = __builtin_amdgcn_mfma_f32_16x16x32_bf16(a, b0, acc0, 0, 0, 0);
        acc1 = __builtin_amdgcn_mfma_f32_16x16x32_bf16(a, b1, acc1, 0, 0, 0);
        acc2 = __builtin_amdgcn_mfma_f32_16x16x32_bf16(a, b2, acc2, 0, 0, 0);
    }

    // epilogue: C row = row0 + rt*16 + quad*4 + r, col h = fw*16 + n
    const int h = fw * 16 + n;
    const size_t g0 = (size_t)(row0 + rt * 16 + quad * 4) * HH + h; // row r=0

    unsigned int uq01 = pkbf2(acc0[0] * SC2F, acc0[1] * SC2F);
    unsigned int uq23 = pkbf2(acc0[2] * SC2F, acc0[3] * SC2F);
    unsigned int uk01 = pkbf2(acc1[0], acc1[1]);
    unsigned int uk23 = pkbf2(acc1[2], acc1[3]);
    qb[g0]          = (unsigned short)uq01;
    qb[g0 + HH]     = (unsigned short)(uq01 >> 16);
    qb[g0 + 2 * HH] = (unsigned short)uq23;
    qb[g0 + 3 * HH] = (unsigned short)(uq23 >> 16);
    kb[g0]          = (unsigned short)uk01;
    kb[g0 + HH]     = (unsigned short)(uk01 >> 16);
    kb[g0 + 2 * HH] = (unsigned short)uk23;
    kb[g0 + 3 * HH] = (unsigned short)(uk23 >> 16);
#pragma unroll
    for (int r = 0; r < 4; ++r) {
        out[NKV + g0 + (size_t)r * HH]     = acc1[r];
        out[2 * NKV + g0 + (size_t)r * HH] = acc2[r];
    }
    // vT rows r=0..3 are consecutive t positions -> one b64 store
    uint2 uv;
    uv.x = pkbf2(acc2[0], acc2[1]);
    uv.y = pkbf2(acc2[2], acc2[3]);
    *(uint2*)&vT[(size_t)(b * HH + h) * TT + ((row0 + rt * 16) & 2047) + quad * 4] = uv;
}

// ---------------------------------------------------------------------------
// attn_mfma v6: R12 per-tile math + K-range z-split. Grid (128,4,2) x 4
// waves; qt = (b<2) ? x : 127-x (balance remap). Block z covers kt =
// z*4+wave, stride 8. Per tile: batched K loads -> 8 QK MFMA -> V loads
// issued (hidden under exp/LDS) -> p = exp2(sc) -> P via wave-private LDS
// -> 8 PV MFMA. In-block merge as before; then partial O/l to ws + flag
// handshake, second arriver writes the final normalized out.
// ---------------------------------------------------------------------------
__global__ __launch_bounds__(256) void attn_mfma(float* __restrict__ out,
                                                 const unsigned short* __restrict__ qb,
                                                 const unsigned short* __restrict__ kb,
                                                 const unsigned short* __restrict__ vT,
                                                 unsigned int* __restrict__ flags,
                                                 float* __restrict__ Lpart,
                                                 float* __restrict__ Opart) {
    __shared__ __align__(16) unsigned short Ps[4][16][72]; // 9.2KB
    __shared__ float Lb[4][64][4];                         // 4KB
    __shared__ float Ob[4][64][16];                        // 16KB

    const int t    = threadIdx.x;
    const int wave = t >> 6, lane = t & 63;
    const int n    = lane & 15, quad = lane >> 4;
    const int b    = blockIdx.y;
    const int z    = blockIdx.z;
    const int qt   = (b < 2) ? blockIdx.x : 127 - blockIdx.x; // balance remap
    const int q0   = qt * 16;

    // Q A-fragments (pre-scaled by SC2): row = q0 + n
    const unsigned short* qr = qb + (size_t)(b * TT + q0 + n) * HH + quad * 8;
    short8 aq0 = *(const short8*)(qr);
    short8 aq1 = *(const short8*)(qr + 32);

    f32x4 oc[4];
#pragma unroll
    for (int d = 0; d < 4; ++d) oc[d] = (f32x4){0.f, 0.f, 0.f, 0.f};
    float l_[4] = {0.f, 0.f, 0.f, 0.f};

    const int nkt = (q0 >> 6) + 1;

    for (int kt = z * 4 + wave; kt < nkt; kt += 8) {
        const int j0 = kt * 64;

        // ---- batched K fragment loads ----
        short8 bk0[4], bk1[4];
#pragma unroll
        for (int s = 0; s < 4; ++s) {
            const unsigned short* kr = kb + (size_t)(b * TT + j0 + s * 16 + n) * HH + quad * 8;
            bk0[s] = *(const short8*)(kr);
            bk1[s] = *(const short8*)(kr + 32);
        }

        // ---- V fragment loads issued NOW; consumed after exp/LDS phase ----
        short8 bv0[4], bv1[4];
#pragma unroll
        for (int d = 0; d < 4; ++d) {
            const unsigned short* vr = vT + (size_t)(b * HH + d * 16 + n) * TT + j0 + quad * 8;
            bv0[d] = *(const short8*)(vr);
            bv1[d] = *(const short8*)(vr + 32);
        }

        // ---- scores (base-2 logits; q pre-scaled) ----
        f32x4 sc[4];
#pragma unroll
        for (int s = 0; s < 4; ++s) sc[s] = (f32x4){0.f, 0.f, 0.f, 0.f};
        __builtin_amdgcn_s_setprio(1);
#pragma unroll
        for (int s = 0; s < 4; ++s) {
            sc[s] = __builtin_amdgcn_mfma_f32_16x16x32_bf16(aq0, bk0[s], sc[s], 0, 0, 0);
            sc[s] = __builtin_amdgcn_mfma_f32_16x16x32_bf16(aq1, bk1[s], sc[s], 0, 0, 0);
        }
        __builtin_amdgcn_s_setprio(0);

        // ---- p = exp2(sc), masked only on the (single) diagonal tile ----
        float p[4][4]; // [s][r]
        if (j0 + 63 <= q0) { // full tile (wave-uniform)
#pragma unroll
            for (int s = 0; s < 4; ++s)
#pragma unroll
                for (int r = 0; r < 4; ++r) {
                    float pe = exp2f(sc[s][r]);
                    p[s][r] = pe;
                    l_[r] += pe;
                }
        } else { // diagonal tile
#pragma unroll
            for (int r = 0; r < 4; ++r) {
                const int qrow = q0 + quad * 4 + r;
#pragma unroll
                for (int s = 0; s < 4; ++s) {
                    int krow = j0 + s * 16 + n;
                    float pe = (krow <= qrow) ? exp2f(sc[s][r]) : 0.f;
                    p[s][r] = pe;
                    l_[r] += pe;
                }
            }
        }

        // ---- P: C-layout -> wave-private LDS -> A-layout (proven R9/R10) ----
#pragma unroll
        for (int s = 0; s < 4; ++s) {
            unsigned int u01 = pkbf2(p[s][0], p[s][1]);
            unsigned int u23 = pkbf2(p[s][2], p[s][3]);
            Ps[wave][quad * 4 + 0][s * 16 + n] = (unsigned short)u01;
            Ps[wave][quad * 4 + 1][s * 16 + n] = (unsigned short)(u01 >> 16);
            Ps[wave][quad * 4 + 2][s * 16 + n] = (unsigned short)u23;
            Ps[wave][quad * 4 + 3][s * 16 + n] = (unsigned short)(u23 >> 16);
        }
        __asm__ volatile("s_waitcnt lgkmcnt(0)" ::: "memory");
        short8 ap0 = *(const short8*)&Ps[wave][n][quad * 8];
        short8 ap1 = *(const short8*)&Ps[wave][n][32 + quad * 8];

        // ---- O += P @ V (V already in registers) ----
        __builtin_amdgcn_s_setprio(1);
#pragma unroll
        for (int d = 0; d < 4; ++d) {
            oc[d] = __builtin_amdgcn_mfma_f32_16x16x32_bf16(ap0, bv0[d], oc[d], 0, 0, 0);
            oc[d] = __builtin_amdgcn_mfma_f32_16x16x32_bf16(ap1, bv1[d], oc[d], 0, 0, 0);
        }
        __builtin_amdgcn_s_setprio(0);
    }

    // ---- deferred l reduction across the 16 lanes sharing a row set ----
#pragma unroll
    for (int off = 1; off < 16; off <<= 1)
#pragma unroll
        for (int r = 0; r < 4; ++r)
            l_[r] += __shfl_xor(l_[r], off);

    // ---- in-block cross-wave sum-merge ----
#pragma unroll
    for (int r = 0; r < 4; ++r) Lb[wave][lane][r] = l_[r];
#pragma unroll
    for (int d = 0; d < 4; ++d)
#pragma unroll
        for (int r = 0; r < 4; ++r)
            Ob[wave][lane][d * 4 + r] = oc[d][r];
    __syncthreads();

    if (wave == 0) {
        float ls_[4], ob_[4][4]; // [r], [d][r]
#pragma unroll
        for (int r = 0; r < 4; ++r)
            ls_[r] = Lb[0][lane][r] + Lb[1][lane][r] + Lb[2][lane][r] + Lb[3][lane][r];
#pragma unroll
        for (int d = 0; d < 4; ++d)
#pragma unroll
            for (int r = 0; r < 4; ++r)
                ob_[d][r] = Ob[0][lane][d * 4 + r] + Ob[1][lane][d * 4 + r] +
                            Ob[2][lane][d * 4 + r] + Ob[3][lane][d * 4 + r];

        const int pidx = b * 128 + qt;
        float* Op = Opart + ((size_t)pidx * 2 + z) * 1024; // 16 rows x 64 cols
#pragma unroll
        for (int r = 0; r < 4; ++r)
#pragma unroll
            for (int d = 0; d < 4; ++d)
                Op[(quad * 4 + r) * 64 + d * 16 + n] = ob_[d][r];
        if (n == 0) {
#pragma unroll
            for (int r = 0; r < 4; ++r)
                Lpart[(pidx * 2 + z) * 16 + quad * 4 + r] = ls_[r];
        }
        __threadfence();
        unsigned int old = 0;
        if (lane == 0) old = atomicAdd(&flags[pidx], 1u);
        old = (unsigned int)__shfl((int)old, 0);
        if (old == 1) { // second arriver: combine + write final
            __threadfence();
            const float* Oo = Opart + ((size_t)pidx * 2 + (z ^ 1)) * 1024;
            const float* Lo = Lpart + (pidx * 2 + (z ^ 1)) * 16;
#pragma unroll
            for (int r = 0; r < 4; ++r) {
                const float ls = ls_[r] + Lo[quad * 4 + r];
                const float inv = 1.f / ls;
#pragma unroll
                for (int d = 0; d < 4; ++d) {
                    float o = ob_[d][r] + Oo[(quad * 4 + r) * 64 + d * 16 + n];
                    out[(size_t)(b * TT + q0 + quad * 4 + r) * HH + d * 16 + n] = o * inv;
                }
            }
        }
    }
}

// ---------------------------------------------------------------------------
extern "C" void kernel_launch(void* const* d_in, const int* in_sizes, int n_in,
                              void* d_out, int out_size, void* d_ws, size_t ws_size,
                              hipStream_t stream) {
    const float* x  = (const float*)d_in[0];
    const float* Wq = (const float*)d_in[1];
    const float* Wk = (const float*)d_in[2];
    const float* Wv = (const float*)d_in[3];
    float* out = (float*)d_out;

    char* ws = (char*)d_ws;
    unsigned short* Wb = (unsigned short*)(ws);              // 384 KB
    unsigned short* qb = (unsigned short*)(ws + (1u << 20)); // 1 MB
    unsigned short* kb = (unsigned short*)(ws + (2u << 20)); // 1 MB
    unsigned short* vT = (unsigned short*)(ws + (3u << 20)); // 1 MB
    unsigned int* flags = (unsigned int*)(ws + (4u << 20));            // 2 KB
    float* Lpart = (float*)(ws + (4u << 20) + 8192);                   // 64 KB
    float* Opart = (float*)(ws + (4u << 20) + (128u << 10));           // 4 MB

    prep_wb<<<768, 256, 0, stream>>>(Wq, Wk, Wv, Wb, flags);
    qkv_mfma<<<256, 512, 0, stream>>>(x, Wb, out, qb, kb, vT);
    attn_mfma<<<dim3(128, 4, 2), 256, 0, stream>>>(out, qb, kb, vT, flags, Lpart, Opart);
}

// Round 8
// 109.910 us; speedup vs baseline: 1.3810x; 1.3810x over previous
//
#include <hip/hip_runtime.h>
#include <hip/hip_bf16.h>
#include <stdint.h>

// Single attention head. B=4, T=2048, C=1024, H=64. FP32 in/out (proven).
// Outputs concat fp32: out[B,T,H], k[B,T,H], v[B,T,H]. scale = 1/32.
//
// R19 = R15 (proven 106.9us: qkv 32-row Wb-reuse + attn R12-exact) + attn
// kt-loop software pipeline:
//  - R18's z-split + __threadfence handshake measured 65us attn with ~0%
//    util: device-scope fences on non-coherent per-XCD L2s serialize the
//    dispatch (writeback storm). Cross-block merge abandoned.
//  - Instead: per-wave prefetch. K/V fragments for tile kt+4 (this wave's
//    next tile) are loaded at the top of iteration kt -> L2 latency
//    (~200-400cy) hides under the current tile's QK/exp/LDS/PV chain.
//    No sync, no geometry change, same math. +32 VGPR (~104-136 total).
// ws (4 MB): [0) Wb 384KB; [1MB) qb; [2MB) kb; [3MB) vT (1MB each, bf16).

#define NB 4
#define TT 2048
#define CC 1024
#define HH 64
#define NKV (NB * TT * HH)

typedef __attribute__((ext_vector_type(8))) short short8; // 8 bf16 = 4 VGPRs
typedef __attribute__((ext_vector_type(4))) float f32x4;  // MFMA C/D

__device__ __forceinline__ unsigned short f2bf(float f) {
    union { float f; unsigned int i; } v;
    v.f = f;
    unsigned int r = v.i + 0x7fffu + ((v.i >> 16) & 1u); // RNE
    return (unsigned short)(r >> 16);
}
// packed RNE f32x2 -> bf16x2 (v_cvt_pk_bf16_f32 on gfx950)
__device__ __forceinline__ unsigned int pkbf2(float a, float b) {
    __hip_bfloat162 h = __float22bfloat162_rn(make_float2(a, b));
    union { __hip_bfloat162 h; unsigned int u; } c;
    c.h = h;
    return c.u;
}

// ---------------------------------------------------------------------------
// prep_wb (R9/R10-proven): Wb[((s*32+kk)*64 + l)*8 + j] =
// W_m[k = 32kk + (l>>4)*8 + j][h = (s&3)*16 + (l&15)], m = s>>2.
// ---------------------------------------------------------------------------
__global__ __launch_bounds__(256) void prep_wb(const float* __restrict__ Wq,
                                               const float* __restrict__ Wk,
                                               const float* __restrict__ Wv,
                                               unsigned short* __restrict__ Wb) {
    int gid = blockIdx.x * 256 + threadIdx.x; // 0 .. 196607
    int j  = gid & 7;
    int l  = (gid >> 3) & 63;
    int kk = (gid >> 9) & 31;
    int s  = gid >> 14;
    int k  = kk * 32 + (l >> 4) * 8 + j;
    int h  = (s & 3) * 16 + (l & 15);
    const float* W = (s >> 2) == 0 ? Wq : (s >> 2) == 1 ? Wk : Wv;
    Wb[gid] = f2bf(W[(size_t)k * HH + h]);
}

// ---------------------------------------------------------------------------
// qkv_mfma v2 (R15-proven): 256 blocks x 512 threads, 32 rows/block, 8 waves.
// Wave w: row-tile rt = w>>2, frag set fw = w&3. x staged to LDS bf16,
// 32x1024, XOR-swizzled on 8B units: phys_u = u ^ ((row&7)<<1).
// ---------------------------------------------------------------------------
#define SC2F 0.0450842200113808f // (1/32)*log2(e)

__global__ __launch_bounds__(512) void qkv_mfma(const float* __restrict__ x,
                                                const unsigned short* __restrict__ Wb,
                                                float* __restrict__ out,
                                                unsigned short* __restrict__ qb,
                                                unsigned short* __restrict__ kb,
                                                unsigned short* __restrict__ vT) {
    __shared__ __align__(16) unsigned short xs[32 * 1024]; // 64KB exactly
    const int t    = threadIdx.x;
    const int wave = t >> 6, lane = t & 63;
    const int n    = lane & 15, quad = lane >> 4;
    const int fw   = wave & 3, rt = wave >> 2;
    const int row0 = blockIdx.x * 32;
    const int b    = row0 >> 11;

    // stage x tile (32 rows x 1024) fp32 -> bf16, swizzled write
    {
        const int tr = t >> 8, tc = t & 255; // tc = 8B unit within row
#pragma unroll 8
        for (int it = 0; it < 16; ++it) {
            const int i = it * 2 + tr;
            float4 f = *(const float4*)(x + (size_t)(row0 + i) * CC + 4 * tc);
            uint2 u;
            u.x = pkbf2(f.x, f.y);
            u.y = pkbf2(f.z, f.w);
            *(uint2*)&xs[i * 1024 + ((tc ^ ((i & 7) << 1)) << 2)] = u;
        }
    }
    __syncthreads();

    f32x4 acc0 = (f32x4){0.f, 0.f, 0.f, 0.f};
    f32x4 acc1 = acc0, acc2 = acc0;

    const unsigned short* wp = Wb + (size_t)lane * 8;
    const size_t fs = (size_t)32 * 64 * 8; // frag-s stride
    const int arow = (rt * 16 + n) * 1024;
    const int axor = (n & 7) << 1;

#pragma unroll 4
    for (int kk = 0; kk < 32; ++kk) {
        short8 a = *(const short8*)&xs[arow + (((kk * 8 + quad * 2) ^ axor) << 2)];
        const unsigned short* wk_ = wp + (size_t)kk * 512;
        short8 b0 = *(const short8*)(wk_ + (size_t)(fw)     * fs);
        short8 b1 = *(const short8*)(wk_ + (size_t)(fw + 4) * fs);
        short8 b2 = *(const short8*)(wk_ + (size_t)(fw + 8) * fs);
        acc0 = __builtin_amdgcn_mfma_f32_16x16x32_bf16(a, b0, acc0, 0, 0, 0);
        acc1 = __builtin_amdgcn_mfma_f32_16x16x32_bf16(a, b1, acc1, 0, 0, 0);
        acc2 = __builtin_amdgcn_mfma_f32_16x16x32_bf16(a, b2, acc2, 0, 0, 0);
    }

    // epilogue: C row = row0 + rt*16 + quad*4 + r, col h = fw*16 + n
    const int h = fw * 16 + n;
    const size_t g0 = (size_t)(row0 + rt * 16 + quad * 4) * HH + h; // row r=0

    unsigned int uq01 = pkbf2(acc0[0] * SC2F, acc0[1] * SC2F);
    unsigned int uq23 = pkbf2(acc0[2] * SC2F, acc0[3] * SC2F);
    unsigned int uk01 = pkbf2(acc1[0], acc1[1]);
    unsigned int uk23 = pkbf2(acc1[2], acc1[3]);
    qb[g0]          = (unsigned short)uq01;
    qb[g0 + HH]     = (unsigned short)(uq01 >> 16);
    qb[g0 + 2 * HH] = (unsigned short)uq23;
    qb[g0 + 3 * HH] = (unsigned short)(uq23 >> 16);
    kb[g0]          = (unsigned short)uk01;
    kb[g0 + HH]     = (unsigned short)(uk01 >> 16);
    kb[g0 + 2 * HH] = (unsigned short)uk23;
    kb[g0 + 3 * HH] = (unsigned short)(uk23 >> 16);
#pragma unroll
    for (int r = 0; r < 4; ++r) {
        out[NKV + g0 + (size_t)r * HH]     = acc1[r];
        out[2 * NKV + g0 + (size_t)r * HH] = acc2[r];
    }
    // vT rows r=0..3 are consecutive t positions -> one b64 store
    uint2 uv;
    uv.x = pkbf2(acc2[0], acc2[1]);
    uv.y = pkbf2(acc2[2], acc2[3]);
    *(uint2*)&vT[(size_t)(b * HH + h) * TT + ((row0 + rt * 16) & 2047) + quad * 4] = uv;
}

// ---------------------------------------------------------------------------
// attn_mfma v7: R12 structure + per-wave kt prefetch pipeline. Grid (128
// x-tiles, 4 batches) x 4 waves; qt = (b<2) ? x : 127-x. Waves split K-tiles
// (kt = w mod 4). Iteration kt: issue K/V loads for kt+4 (next tile of THIS
// wave) first, then compute tile kt from the previously-loaded registers:
// 8 QK MFMA -> p = exp2(sc) -> P via wave-private LDS -> 8 PV MFMA.
// l deferred; cross-wave merge is a plain in-block sum (no global sync).
// ---------------------------------------------------------------------------
__global__ __launch_bounds__(256) void attn_mfma(float* __restrict__ out,
                                                 const unsigned short* __restrict__ qb,
                                                 const unsigned short* __restrict__ kb,
                                                 const unsigned short* __restrict__ vT) {
    __shared__ __align__(16) unsigned short Ps[4][16][72]; // 9.2KB
    __shared__ float Lb[4][64][4];                         // 4KB
    __shared__ float Ob[4][64][16];                        // 16KB

    const int t    = threadIdx.x;
    const int wave = t >> 6, lane = t & 63;
    const int n    = lane & 15, quad = lane >> 4;
    const int b    = blockIdx.y;
    const int qt   = (b < 2) ? blockIdx.x : 127 - blockIdx.x; // balance remap
    const int q0   = qt * 16;

    // Q A-fragments (pre-scaled by SC2): row = q0 + n
    const unsigned short* qr = qb + (size_t)(b * TT + q0 + n) * HH + quad * 8;
    short8 aq0 = *(const short8*)(qr);
    short8 aq1 = *(const short8*)(qr + 32);

    f32x4 oc[4];
#pragma unroll
    for (int d = 0; d < 4; ++d) oc[d] = (f32x4){0.f, 0.f, 0.f, 0.f};
    float l_[4] = {0.f, 0.f, 0.f, 0.f};

    const int nkt = (q0 >> 6) + 1;

    // ---- prefetch first tile (valid dummy address if wave has no work) ----
    short8 ck0[4], ck1[4], cv0[4], cv1[4];
    {
        const int jp = (wave < nkt ? wave : 0) * 64;
#pragma unroll
        for (int s = 0; s < 4; ++s) {
            const unsigned short* kr = kb + (size_t)(b * TT + jp + s * 16 + n) * HH + quad * 8;
            ck0[s] = *(const short8*)(kr);
            ck1[s] = *(const short8*)(kr + 32);
        }
#pragma unroll
        for (int d = 0; d < 4; ++d) {
            const unsigned short* vr = vT + (size_t)(b * HH + d * 16 + n) * TT + jp + quad * 8;
            cv0[d] = *(const short8*)(vr);
            cv1[d] = *(const short8*)(vr + 32);
        }
    }

    for (int kt = wave; kt < nkt; kt += 4) {
        const int j0 = kt * 64;

        // ---- issue NEXT tile's K/V loads (hidden under this tile's chain) --
        short8 nk0[4], nk1[4], nv0[4], nv1[4];
        {
            const int jn = (kt + 4 < nkt ? kt + 4 : kt) * 64;
#pragma unroll
            for (int s = 0; s < 4; ++s) {
                const unsigned short* kr = kb + (size_t)(b * TT + jn + s * 16 + n) * HH + quad * 8;
                nk0[s] = *(const short8*)(kr);
                nk1[s] = *(const short8*)(kr + 32);
            }
#pragma unroll
            for (int d = 0; d < 4; ++d) {
                const unsigned short* vr = vT + (size_t)(b * HH + d * 16 + n) * TT + jn + quad * 8;
                nv0[d] = *(const short8*)(vr);
                nv1[d] = *(const short8*)(vr + 32);
            }
        }

        // ---- scores (base-2 logits; q pre-scaled) ----
        f32x4 sc[4];
#pragma unroll
        for (int s = 0; s < 4; ++s) sc[s] = (f32x4){0.f, 0.f, 0.f, 0.f};
        __builtin_amdgcn_s_setprio(1);
#pragma unroll
        for (int s = 0; s < 4; ++s) {
            sc[s] = __builtin_amdgcn_mfma_f32_16x16x32_bf16(aq0, ck0[s], sc[s], 0, 0, 0);
            sc[s] = __builtin_amdgcn_mfma_f32_16x16x32_bf16(aq1, ck1[s], sc[s], 0, 0, 0);
        }
        __builtin_amdgcn_s_setprio(0);

        // ---- p = exp2(sc), masked only on the (single) diagonal tile ----
        float p[4][4]; // [s][r]
        if (j0 + 63 <= q0) { // full tile (wave-uniform)
#pragma unroll
            for (int s = 0; s < 4; ++s)
#pragma unroll
                for (int r = 0; r < 4; ++r) {
                    float pe = exp2f(sc[s][r]);
                    p[s][r] = pe;
                    l_[r] += pe;
                }
        } else { // diagonal tile
#pragma unroll
            for (int r = 0; r < 4; ++r) {
                const int qrow = q0 + quad * 4 + r;
#pragma unroll
                for (int s = 0; s < 4; ++s) {
                    int krow = j0 + s * 16 + n;
                    float pe = (krow <= qrow) ? exp2f(sc[s][r]) : 0.f;
                    p[s][r] = pe;
                    l_[r] += pe;
                }
            }
        }

        // ---- P: C-layout -> wave-private LDS -> A-layout (proven R9/R10) ----
#pragma unroll
        for (int s = 0; s < 4; ++s) {
            unsigned int u01 = pkbf2(p[s][0], p[s][1]);
            unsigned int u23 = pkbf2(p[s][2], p[s][3]);
            Ps[wave][quad * 4 + 0][s * 16 + n] = (unsigned short)u01;
            Ps[wave][quad * 4 + 1][s * 16 + n] = (unsigned short)(u01 >> 16);
            Ps[wave][quad * 4 + 2][s * 16 + n] = (unsigned short)u23;
            Ps[wave][quad * 4 + 3][s * 16 + n] = (unsigned short)(u23 >> 16);
        }
        __asm__ volatile("s_waitcnt lgkmcnt(0)" ::: "memory");
        short8 ap0 = *(const short8*)&Ps[wave][n][quad * 8];
        short8 ap1 = *(const short8*)&Ps[wave][n][32 + quad * 8];

        // ---- O += P @ V (V loaded a full iteration ago) ----
        __builtin_amdgcn_s_setprio(1);
#pragma unroll
        for (int d = 0; d < 4; ++d) {
            oc[d] = __builtin_amdgcn_mfma_f32_16x16x32_bf16(ap0, cv0[d], oc[d], 0, 0, 0);
            oc[d] = __builtin_amdgcn_mfma_f32_16x16x32_bf16(ap1, cv1[d], oc[d], 0, 0, 0);
        }
        __builtin_amdgcn_s_setprio(0);

        // ---- rotate prefetch buffers ----
#pragma unroll
        for (int s = 0; s < 4; ++s) {
            ck0[s] = nk0[s]; ck1[s] = nk1[s];
            cv0[s] = nv0[s]; cv1[s] = nv1[s];
        }
    }

    // ---- deferred l reduction across the 16 lanes sharing a row set ----
#pragma unroll
    for (int off = 1; off < 16; off <<= 1)
#pragma unroll
        for (int r = 0; r < 4; ++r)
            l_[r] += __shfl_xor(l_[r], off);

    // ---- cross-wave sum-merge ----
#pragma unroll
    for (int r = 0; r < 4; ++r) Lb[wave][lane][r] = l_[r];
#pragma unroll
    for (int d = 0; d < 4; ++d)
#pragma unroll
        for (int r = 0; r < 4; ++r)
            Ob[wave][lane][d * 4 + r] = oc[d][r];
    __syncthreads();

    if (wave == 0) {
#pragma unroll
        for (int r = 0; r < 4; ++r) {
            float ls = Lb[0][lane][r] + Lb[1][lane][r] + Lb[2][lane][r] + Lb[3][lane][r];
            const float inv = 1.f / ls;
#pragma unroll
            for (int d = 0; d < 4; ++d) {
                float o = Ob[0][lane][d * 4 + r] + Ob[1][lane][d * 4 + r] +
                          Ob[2][lane][d * 4 + r] + Ob[3][lane][d * 4 + r];
                out[(size_t)(b * TT + q0 + quad * 4 + r) * HH + d * 16 + n] = o * inv;
            }
        }
    }
}

// ---------------------------------------------------------------------------
extern "C" void kernel_launch(void* const* d_in, const int* in_sizes, int n_in,
                              void* d_out, int out_size, void* d_ws, size_t ws_size,
                              hipStream_t stream) {
    const float* x  = (const float*)d_in[0];
    const float* Wq = (const float*)d_in[1];
    const float* Wk = (const float*)d_in[2];
    const float* Wv = (const float*)d_in[3];
    float* out = (float*)d_out;

    char* ws = (char*)d_ws;
    unsigned short* Wb = (unsigned short*)(ws);              // 384 KB
    unsigned short* qb = (unsigned short*)(ws + (1u << 20)); // 1 MB
    unsigned short* kb = (unsigned short*)(ws + (2u << 20)); // 1 MB
    unsigned short* vT = (unsigned short*)(ws + (3u << 20)); // 1 MB

    prep_wb<<<768, 256, 0, stream>>>(Wq, Wk, Wv, Wb);
    qkv_mfma<<<256, 512, 0, stream>>>(x, Wb, out, qb, kb, vT);
    attn_mfma<<<dim3(128, 4), 256, 0, stream>>>(out, qb, kb, vT);
}

// Round 9
// 108.621 us; speedup vs baseline: 1.3974x; 1.0119x over previous
//
#include <hip/hip_runtime.h>
#include <hip/hip_bf16.h>
#include <stdint.h>

// Single attention head. B=4, T=2048, C=1024, H=64. FP32 in/out (proven).
// Outputs concat fp32: out[B,T,H], k[B,T,H], v[B,T,H]. scale = 1/32.
//
// R20 = R15 (proven 106.9us) with attn widened 4 -> 8 waves per block:
//  - attn: grid (128,4) x 512 threads. kt = wave (mod 8): critical wave
//    path 8 -> 4 tiles; 16 waves/CU (4/SIMD, was 2) for latency hiding.
//    Per-wave code BYTE-IDENTICAL to the proven R12/R15 tile pipeline
//    (batched K loads, V-hoist, setprio, static-max softmax, single
//    diagonal tile). Merge sums 8 partials. No fences (R18 lesson), no
//    reg rotation (R19 lesson: rotate forces vmcnt(0) -> nullifies
//    prefetch + adds 64 v_mov/iter), no variable strides (R14 lesson).
//  - qkv/prep unchanged from R15 for attribution.
// ws (4 MB): [0) Wb 384KB; [1MB) qb; [2MB) kb; [3MB) vT (1MB each, bf16).

#define NB 4
#define TT 2048
#define CC 1024
#define HH 64
#define NKV (NB * TT * HH)

typedef __attribute__((ext_vector_type(8))) short short8; // 8 bf16 = 4 VGPRs
typedef __attribute__((ext_vector_type(4))) float f32x4;  // MFMA C/D

__device__ __forceinline__ unsigned short f2bf(float f) {
    union { float f; unsigned int i; } v;
    v.f = f;
    unsigned int r = v.i + 0x7fffu + ((v.i >> 16) & 1u); // RNE
    return (unsigned short)(r >> 16);
}
// packed RNE f32x2 -> bf16x2 (v_cvt_pk_bf16_f32 on gfx950)
__device__ __forceinline__ unsigned int pkbf2(float a, float b) {
    __hip_bfloat162 h = __float22bfloat162_rn(make_float2(a, b));
    union { __hip_bfloat162 h; unsigned int u; } c;
    c.h = h;
    return c.u;
}

// ---------------------------------------------------------------------------
// prep_wb (R9/R10-proven): Wb[((s*32+kk)*64 + l)*8 + j] =
// W_m[k = 32kk + (l>>4)*8 + j][h = (s&3)*16 + (l&15)], m = s>>2.
// ---------------------------------------------------------------------------
__global__ __launch_bounds__(256) void prep_wb(const float* __restrict__ Wq,
                                               const float* __restrict__ Wk,
                                               const float* __restrict__ Wv,
                                               unsigned short* __restrict__ Wb) {
    int gid = blockIdx.x * 256 + threadIdx.x; // 0 .. 196607
    int j  = gid & 7;
    int l  = (gid >> 3) & 63;
    int kk = (gid >> 9) & 31;
    int s  = gid >> 14;
    int k  = kk * 32 + (l >> 4) * 8 + j;
    int h  = (s & 3) * 16 + (l & 15);
    const float* W = (s >> 2) == 0 ? Wq : (s >> 2) == 1 ? Wk : Wv;
    Wb[gid] = f2bf(W[(size_t)k * HH + h]);
}

// ---------------------------------------------------------------------------
// qkv_mfma v2 (R15-proven): 256 blocks x 512 threads, 32 rows/block, 8 waves.
// Wave w: row-tile rt = w>>2, frag set fw = w&3. x staged to LDS bf16,
// 32x1024, XOR-swizzled on 8B units: phys_u = u ^ ((row&7)<<1).
// ---------------------------------------------------------------------------
#define SC2F 0.0450842200113808f // (1/32)*log2(e)

__global__ __launch_bounds__(512) void qkv_mfma(const float* __restrict__ x,
                                                const unsigned short* __restrict__ Wb,
                                                float* __restrict__ out,
                                                unsigned short* __restrict__ qb,
                                                unsigned short* __restrict__ kb,
                                                unsigned short* __restrict__ vT) {
    __shared__ __align__(16) unsigned short xs[32 * 1024]; // 64KB exactly
    const int t    = threadIdx.x;
    const int wave = t >> 6, lane = t & 63;
    const int n    = lane & 15, quad = lane >> 4;
    const int fw   = wave & 3, rt = wave >> 2;
    const int row0 = blockIdx.x * 32;
    const int b    = row0 >> 11;

    // stage x tile (32 rows x 1024) fp32 -> bf16, swizzled write
    {
        const int tr = t >> 8, tc = t & 255; // tc = 8B unit within row
#pragma unroll 8
        for (int it = 0; it < 16; ++it) {
            const int i = it * 2 + tr;
            float4 f = *(const float4*)(x + (size_t)(row0 + i) * CC + 4 * tc);
            uint2 u;
            u.x = pkbf2(f.x, f.y);
            u.y = pkbf2(f.z, f.w);
            *(uint2*)&xs[i * 1024 + ((tc ^ ((i & 7) << 1)) << 2)] = u;
        }
    }
    __syncthreads();

    f32x4 acc0 = (f32x4){0.f, 0.f, 0.f, 0.f};
    f32x4 acc1 = acc0, acc2 = acc0;

    const unsigned short* wp = Wb + (size_t)lane * 8;
    const size_t fs = (size_t)32 * 64 * 8; // frag-s stride
    const int arow = (rt * 16 + n) * 1024;
    const int axor = (n & 7) << 1;

#pragma unroll 4
    for (int kk = 0; kk < 32; ++kk) {
        short8 a = *(const short8*)&xs[arow + (((kk * 8 + quad * 2) ^ axor) << 2)];
        const unsigned short* wk_ = wp + (size_t)kk * 512;
        short8 b0 = *(const short8*)(wk_ + (size_t)(fw)     * fs);
        short8 b1 = *(const short8*)(wk_ + (size_t)(fw + 4) * fs);
        short8 b2 = *(const short8*)(wk_ + (size_t)(fw + 8) * fs);
        acc0 = __builtin_amdgcn_mfma_f32_16x16x32_bf16(a, b0, acc0, 0, 0, 0);
        acc1 = __builtin_amdgcn_mfma_f32_16x16x32_bf16(a, b1, acc1, 0, 0, 0);
        acc2 = __builtin_amdgcn_mfma_f32_16x16x32_bf16(a, b2, acc2, 0, 0, 0);
    }

    // epilogue: C row = row0 + rt*16 + quad*4 + r, col h = fw*16 + n
    const int h = fw * 16 + n;
    const size_t g0 = (size_t)(row0 + rt * 16 + quad * 4) * HH + h; // row r=0

    unsigned int uq01 = pkbf2(acc0[0] * SC2F, acc0[1] * SC2F);
    unsigned int uq23 = pkbf2(acc0[2] * SC2F, acc0[3] * SC2F);
    unsigned int uk01 = pkbf2(acc1[0], acc1[1]);
    unsigned int uk23 = pkbf2(acc1[2], acc1[3]);
    qb[g0]          = (unsigned short)uq01;
    qb[g0 + HH]     = (unsigned short)(uq01 >> 16);
    qb[g0 + 2 * HH] = (unsigned short)uq23;
    qb[g0 + 3 * HH] = (unsigned short)(uq23 >> 16);
    kb[g0]          = (unsigned short)uk01;
    kb[g0 + HH]     = (unsigned short)(uk01 >> 16);
    kb[g0 + 2 * HH] = (unsigned short)uk23;
    kb[g0 + 3 * HH] = (unsigned short)(uk23 >> 16);
#pragma unroll
    for (int r = 0; r < 4; ++r) {
        out[NKV + g0 + (size_t)r * HH]     = acc1[r];
        out[2 * NKV + g0 + (size_t)r * HH] = acc2[r];
    }
    // vT rows r=0..3 are consecutive t positions -> one b64 store
    uint2 uv;
    uv.x = pkbf2(acc2[0], acc2[1]);
    uv.y = pkbf2(acc2[2], acc2[3]);
    *(uint2*)&vT[(size_t)(b * HH + h) * TT + ((row0 + rt * 16) & 2047) + quad * 4] = uv;
}

// ---------------------------------------------------------------------------
// attn_mfma v8: R12/R15 per-tile pipeline, widened to 8 waves/block.
// Grid (128 x-tiles, 4 batches) x 512 threads; qt = (b<2) ? x : 127-x.
// Waves split K-tiles 8 ways (kt = wave mod 8): critical wave 4 tiles.
// Per tile: batched K loads -> 8 QK MFMA -> V loads issued (hidden under
// exp/LDS) -> p = exp2(sc) -> P via wave-private LDS -> 8 PV MFMA.
// l deferred to one post-loop lane-reduction; in-block merge sums 8 waves.
// Exactly one masked (diagonal) tile per q-tile.
// ---------------------------------------------------------------------------
__global__ __launch_bounds__(512) void attn_mfma(float* __restrict__ out,
                                                 const unsigned short* __restrict__ qb,
                                                 const unsigned short* __restrict__ kb,
                                                 const unsigned short* __restrict__ vT) {
    __shared__ __align__(16) unsigned short Ps[8][16][72]; // 18.4KB
    __shared__ float Lb[8][64][4];                         // 8KB
    __shared__ float Ob[8][64][16];                        // 32KB

    const int t    = threadIdx.x;
    const int wave = t >> 6, lane = t & 63;
    const int n    = lane & 15, quad = lane >> 4;
    const int b    = blockIdx.y;
    const int qt   = (b < 2) ? blockIdx.x : 127 - blockIdx.x; // balance remap
    const int q0   = qt * 16;

    // Q A-fragments (pre-scaled by SC2): row = q0 + n
    const unsigned short* qr = qb + (size_t)(b * TT + q0 + n) * HH + quad * 8;
    short8 aq0 = *(const short8*)(qr);
    short8 aq1 = *(const short8*)(qr + 32);

    f32x4 oc[4];
#pragma unroll
    for (int d = 0; d < 4; ++d) oc[d] = (f32x4){0.f, 0.f, 0.f, 0.f};
    float l_[4] = {0.f, 0.f, 0.f, 0.f};

    const int nkt = (q0 >> 6) + 1;

    for (int kt = wave; kt < nkt; kt += 8) {
        const int j0 = kt * 64;

        // ---- batched K fragment loads ----
        short8 bk0[4], bk1[4];
#pragma unroll
        for (int s = 0; s < 4; ++s) {
            const unsigned short* kr = kb + (size_t)(b * TT + j0 + s * 16 + n) * HH + quad * 8;
            bk0[s] = *(const short8*)(kr);
            bk1[s] = *(const short8*)(kr + 32);
        }

        // ---- V fragment loads issued NOW; consumed after exp/LDS phase ----
        short8 bv0[4], bv1[4];
#pragma unroll
        for (int d = 0; d < 4; ++d) {
            const unsigned short* vr = vT + (size_t)(b * HH + d * 16 + n) * TT + j0 + quad * 8;
            bv0[d] = *(const short8*)(vr);
            bv1[d] = *(const short8*)(vr + 32);
        }

        // ---- scores (base-2 logits; q pre-scaled) ----
        f32x4 sc[4];
#pragma unroll
        for (int s = 0; s < 4; ++s) sc[s] = (f32x4){0.f, 0.f, 0.f, 0.f};
        __builtin_amdgcn_s_setprio(1);
#pragma unroll
        for (int s = 0; s < 4; ++s) {
            sc[s] = __builtin_amdgcn_mfma_f32_16x16x32_bf16(aq0, bk0[s], sc[s], 0, 0, 0);
            sc[s] = __builtin_amdgcn_mfma_f32_16x16x32_bf16(aq1, bk1[s], sc[s], 0, 0, 0);
        }
        __builtin_amdgcn_s_setprio(0);

        // ---- p = exp2(sc), masked only on the (single) diagonal tile ----
        float p[4][4]; // [s][r]
        if (j0 + 63 <= q0) { // full tile (wave-uniform)
#pragma unroll
            for (int s = 0; s < 4; ++s)
#pragma unroll
                for (int r = 0; r < 4; ++r) {
                    float pe = exp2f(sc[s][r]);
                    p[s][r] = pe;
                    l_[r] += pe;
                }
        } else { // diagonal tile
#pragma unroll
            for (int r = 0; r < 4; ++r) {
                const int qrow = q0 + quad * 4 + r;
#pragma unroll
                for (int s = 0; s < 4; ++s) {
                    int krow = j0 + s * 16 + n;
                    float pe = (krow <= qrow) ? exp2f(sc[s][r]) : 0.f;
                    p[s][r] = pe;
                    l_[r] += pe;
                }
            }
        }

        // ---- P: C-layout -> wave-private LDS -> A-layout (proven R9/R10) ----
#pragma unroll
        for (int s = 0; s < 4; ++s) {
            unsigned int u01 = pkbf2(p[s][0], p[s][1]);
            unsigned int u23 = pkbf2(p[s][2], p[s][3]);
            Ps[wave][quad * 4 + 0][s * 16 + n] = (unsigned short)u01;
            Ps[wave][quad * 4 + 1][s * 16 + n] = (unsigned short)(u01 >> 16);
            Ps[wave][quad * 4 + 2][s * 16 + n] = (unsigned short)u23;
            Ps[wave][quad * 4 + 3][s * 16 + n] = (unsigned short)(u23 >> 16);
        }
        __asm__ volatile("s_waitcnt lgkmcnt(0)" ::: "memory");
        short8 ap0 = *(const short8*)&Ps[wave][n][quad * 8];
        short8 ap1 = *(const short8*)&Ps[wave][n][32 + quad * 8];

        // ---- O += P @ V (V already in registers) ----
        __builtin_amdgcn_s_setprio(1);
#pragma unroll
        for (int d = 0; d < 4; ++d) {
            oc[d] = __builtin_amdgcn_mfma_f32_16x16x32_bf16(ap0, bv0[d], oc[d], 0, 0, 0);
            oc[d] = __builtin_amdgcn_mfma_f32_16x16x32_bf16(ap1, bv1[d], oc[d], 0, 0, 0);
        }
        __builtin_amdgcn_s_setprio(0);
    }

    // ---- deferred l reduction across the 16 lanes sharing a row set ----
#pragma unroll
    for (int off = 1; off < 16; off <<= 1)
#pragma unroll
        for (int r = 0; r < 4; ++r)
            l_[r] += __shfl_xor(l_[r], off);

    // ---- cross-wave sum-merge (8 waves) ----
#pragma unroll
    for (int r = 0; r < 4; ++r) Lb[wave][lane][r] = l_[r];
#pragma unroll
    for (int d = 0; d < 4; ++d)
#pragma unroll
        for (int r = 0; r < 4; ++r)
            Ob[wave][lane][d * 4 + r] = oc[d][r];
    __syncthreads();

    if (wave == 0) {
#pragma unroll
        for (int r = 0; r < 4; ++r) {
            float ls = 0.f;
#pragma unroll
            for (int w = 0; w < 8; ++w) ls += Lb[w][lane][r];
            const float inv = 1.f / ls;
#pragma unroll
            for (int d = 0; d < 4; ++d) {
                float o = 0.f;
#pragma unroll
                for (int w = 0; w < 8; ++w) o += Ob[w][lane][d * 4 + r];
                out[(size_t)(b * TT + q0 + quad * 4 + r) * HH + d * 16 + n] = o * inv;
            }
        }
    }
}

// ---------------------------------------------------------------------------
extern "C" void kernel_launch(void* const* d_in, const int* in_sizes, int n_in,
                              void* d_out, int out_size, void* d_ws, size_t ws_size,
                              hipStream_t stream) {
    const float* x  = (const float*)d_in[0];
    const float* Wq = (const float*)d_in[1];
    const float* Wk = (const float*)d_in[2];
    const float* Wv = (const float*)d_in[3];
    float* out = (float*)d_out;

    char* ws = (char*)d_ws;
    unsigned short* Wb = (unsigned short*)(ws);              // 384 KB
    unsigned short* qb = (unsigned short*)(ws + (1u << 20)); // 1 MB
    unsigned short* kb = (unsigned short*)(ws + (2u << 20)); // 1 MB
    unsigned short* vT = (unsigned short*)(ws + (3u << 20)); // 1 MB

    prep_wb<<<768, 256, 0, stream>>>(Wq, Wk, Wv, Wb);
    qkv_mfma<<<256, 512, 0, stream>>>(x, Wb, out, qb, kb, vT);
    attn_mfma<<<dim3(128, 4), 512, 0, stream>>>(out, qb, kb, vT);
}

// Round 10
// 107.390 us; speedup vs baseline: 1.4134x; 1.0115x over previous
//
#include <hip/hip_runtime.h>
#include <hip/hip_bf16.h>
#include <stdint.h>

// Single attention head. B=4, T=2048, C=1024, H=64. FP32 in/out (proven).
// Outputs concat fp32: out[B,T,H], k[B,T,H], v[B,T,H]. scale = 1/32.
//
// R21 = R15-exact (proven 106.9us: qkv 32-row Wb-reuse + attn R12-exact;
// attn-restructure ledger: pooled-pair +6.7, fence-handshake +45,
// reg-prefetch +3.0, 8-wave +1.7 -> R12 attn is the local optimum, frozen)
// + prep_wb v2, coalesced:
//  - old prep: gid->(k,h) mapping gave stride-256B scattered reads
//    (8x32B segments/wave). v2: thread owns 8 consecutive h of one W row
//    -> 8 lanes read a full 256B row contiguously; writes are 8x2B at
//    stride 16B (fire-and-forget). Same Wb layout (index inverse:
//    s=4m+(h>>4), kk=k>>5, j=k&7, l=16*((k>>3)&3)+(h&15); verified).
// ws (4 MB): [0) Wb 384KB; [1MB) qb; [2MB) kb; [3MB) vT (1MB each, bf16).

#define NB 4
#define TT 2048
#define CC 1024
#define HH 64
#define NKV (NB * TT * HH)

typedef __attribute__((ext_vector_type(8))) short short8; // 8 bf16 = 4 VGPRs
typedef __attribute__((ext_vector_type(4))) float f32x4;  // MFMA C/D

__device__ __forceinline__ unsigned short f2bf(float f) {
    union { float f; unsigned int i; } v;
    v.f = f;
    unsigned int r = v.i + 0x7fffu + ((v.i >> 16) & 1u); // RNE
    return (unsigned short)(r >> 16);
}
// packed RNE f32x2 -> bf16x2 (v_cvt_pk_bf16_f32 on gfx950)
__device__ __forceinline__ unsigned int pkbf2(float a, float b) {
    __hip_bfloat162 h = __float22bfloat162_rn(make_float2(a, b));
    union { __hip_bfloat162 h; unsigned int u; } c;
    c.h = h;
    return c.u;
}

// ---------------------------------------------------------------------------
// prep_wb v2 (coalesced reads): thread t handles W_m[k][h0..h0+7].
// 8 lanes = one 256B row read contiguously. Writes: Wb[base + i*8], i=0..7,
// base = ((s*32+kk)*64 + l0)*8 + j with s=4m+(h0>>4), kk=k>>5, j=k&7,
// l0 = 16*((k>>3)&3) + (h0&15). Same Wb layout as R9/R10 (verified inverse).
// Grid: 96 blocks x 256 threads = 24576 threads x 8 elems = 196608.
// ---------------------------------------------------------------------------
__global__ __launch_bounds__(256) void prep_wb(const float* __restrict__ Wq,
                                               const float* __restrict__ Wk,
                                               const float* __restrict__ Wv,
                                               unsigned short* __restrict__ Wb) {
    const int gid = blockIdx.x * 256 + threadIdx.x; // 0..24575
    const int e0  = gid * 8;                        // element index, h fastest
    const int h0  = e0 & 63;                        // multiple of 8
    const int k   = (e0 >> 6) & 1023;
    const int m   = e0 >> 16;                       // 0..2
    const float* W = m == 0 ? Wq : m == 1 ? Wk : Wv;
    const float* src = W + (size_t)k * HH + h0;     // 32B-aligned
    float4 f0 = *(const float4*)(src);
    float4 f1 = *(const float4*)(src + 4);

    const int s  = m * 4 + (h0 >> 4);
    const int kk = k >> 5;
    const int j  = k & 7;
    const int l0 = (((k >> 3) & 3) << 4) + (h0 & 15);
    unsigned short* dst = Wb + ((size_t)(s * 32 + kk) * 64 + l0) * 8 + j;
    dst[0 * 8] = f2bf(f0.x);
    dst[1 * 8] = f2bf(f0.y);
    dst[2 * 8] = f2bf(f0.z);
    dst[3 * 8] = f2bf(f0.w);
    dst[4 * 8] = f2bf(f1.x);
    dst[5 * 8] = f2bf(f1.y);
    dst[6 * 8] = f2bf(f1.z);
    dst[7 * 8] = f2bf(f1.w);
}

// ---------------------------------------------------------------------------
// qkv_mfma v2 (R15-proven): 256 blocks x 512 threads, 32 rows/block, 8 waves.
// Wave w: row-tile rt = w>>2, frag set fw = w&3. x staged to LDS bf16,
// 32x1024, XOR-swizzled on 8B units: phys_u = u ^ ((row&7)<<1).
// ---------------------------------------------------------------------------
#define SC2F 0.0450842200113808f // (1/32)*log2(e)

__global__ __launch_bounds__(512) void qkv_mfma(const float* __restrict__ x,
                                                const unsigned short* __restrict__ Wb,
                                                float* __restrict__ out,
                                                unsigned short* __restrict__ qb,
                                                unsigned short* __restrict__ kb,
                                                unsigned short* __restrict__ vT) {
    __shared__ __align__(16) unsigned short xs[32 * 1024]; // 64KB exactly
    const int t    = threadIdx.x;
    const int wave = t >> 6, lane = t & 63;
    const int n    = lane & 15, quad = lane >> 4;
    const int fw   = wave & 3, rt = wave >> 2;
    const int row0 = blockIdx.x * 32;
    const int b    = row0 >> 11;

    // stage x tile (32 rows x 1024) fp32 -> bf16, swizzled write
    {
        const int tr = t >> 8, tc = t & 255; // tc = 8B unit within row
#pragma unroll 8
        for (int it = 0; it < 16; ++it) {
            const int i = it * 2 + tr;
            float4 f = *(const float4*)(x + (size_t)(row0 + i) * CC + 4 * tc);
            uint2 u;
            u.x = pkbf2(f.x, f.y);
            u.y = pkbf2(f.z, f.w);
            *(uint2*)&xs[i * 1024 + ((tc ^ ((i & 7) << 1)) << 2)] = u;
        }
    }
    __syncthreads();

    f32x4 acc0 = (f32x4){0.f, 0.f, 0.f, 0.f};
    f32x4 acc1 = acc0, acc2 = acc0;

    const unsigned short* wp = Wb + (size_t)lane * 8;
    const size_t fs = (size_t)32 * 64 * 8; // frag-s stride
    const int arow = (rt * 16 + n) * 1024;
    const int axor = (n & 7) << 1;

#pragma unroll 4
    for (int kk = 0; kk < 32; ++kk) {
        short8 a = *(const short8*)&xs[arow + (((kk * 8 + quad * 2) ^ axor) << 2)];
        const unsigned short* wk_ = wp + (size_t)kk * 512;
        short8 b0 = *(const short8*)(wk_ + (size_t)(fw)     * fs);
        short8 b1 = *(const short8*)(wk_ + (size_t)(fw + 4) * fs);
        short8 b2 = *(const short8*)(wk_ + (size_t)(fw + 8) * fs);
        acc0 = __builtin_amdgcn_mfma_f32_16x16x32_bf16(a, b0, acc0, 0, 0, 0);
        acc1 = __builtin_amdgcn_mfma_f32_16x16x32_bf16(a, b1, acc1, 0, 0, 0);
        acc2 = __builtin_amdgcn_mfma_f32_16x16x32_bf16(a, b2, acc2, 0, 0, 0);
    }

    // epilogue: C row = row0 + rt*16 + quad*4 + r, col h = fw*16 + n
    const int h = fw * 16 + n;
    const size_t g0 = (size_t)(row0 + rt * 16 + quad * 4) * HH + h; // row r=0

    unsigned int uq01 = pkbf2(acc0[0] * SC2F, acc0[1] * SC2F);
    unsigned int uq23 = pkbf2(acc0[2] * SC2F, acc0[3] * SC2F);
    unsigned int uk01 = pkbf2(acc1[0], acc1[1]);
    unsigned int uk23 = pkbf2(acc1[2], acc1[3]);
    qb[g0]          = (unsigned short)uq01;
    qb[g0 + HH]     = (unsigned short)(uq01 >> 16);
    qb[g0 + 2 * HH] = (unsigned short)uq23;
    qb[g0 + 3 * HH] = (unsigned short)(uq23 >> 16);
    kb[g0]          = (unsigned short)uk01;
    kb[g0 + HH]     = (unsigned short)(uk01 >> 16);
    kb[g0 + 2 * HH] = (unsigned short)uk23;
    kb[g0 + 3 * HH] = (unsigned short)(uk23 >> 16);
#pragma unroll
    for (int r = 0; r < 4; ++r) {
        out[NKV + g0 + (size_t)r * HH]     = acc1[r];
        out[2 * NKV + g0 + (size_t)r * HH] = acc2[r];
    }
    // vT rows r=0..3 are consecutive t positions -> one b64 store
    uint2 uv;
    uv.x = pkbf2(acc2[0], acc2[1]);
    uv.y = pkbf2(acc2[2], acc2[3]);
    *(uint2*)&vT[(size_t)(b * HH + h) * TT + ((row0 + rt * 16) & 2047) + quad * 4] = uv;
}

// ---------------------------------------------------------------------------
// attn_mfma (R12-exact, proven): static-max flash. Grid (128 x-tiles,
// 4 batches) x 4 waves; qt = (b<2) ? x : 127-x so CU-co-resident blocks have
// complementary causal work. Waves split K-tiles (kt = w mod 4). Per tile:
// batched K loads -> 8 QK MFMA -> V loads issued (hidden under exp/LDS) ->
// p = exp2(sc) -> P via wave-private LDS -> 8 PV MFMA. l deferred to one
// post-loop lane-reduction; cross-wave merge is a plain sum. Exactly one
// masked (diagonal) tile per q-tile.
// ---------------------------------------------------------------------------
__global__ __launch_bounds__(256) void attn_mfma(float* __restrict__ out,
                                                 const unsigned short* __restrict__ qb,
                                                 const unsigned short* __restrict__ kb,
                                                 const unsigned short* __restrict__ vT) {
    __shared__ __align__(16) unsigned short Ps[4][16][72]; // 9.2KB
    __shared__ float Lb[4][64][4];                         // 4KB
    __shared__ float Ob[4][64][16];                        // 16KB

    const int t    = threadIdx.x;
    const int wave = t >> 6, lane = t & 63;
    const int n    = lane & 15, quad = lane >> 4;
    const int b    = blockIdx.y;
    const int qt   = (b < 2) ? blockIdx.x : 127 - blockIdx.x; // balance remap
    const int q0   = qt * 16;

    // Q A-fragments (pre-scaled by SC2): row = q0 + n
    const unsigned short* qr = qb + (size_t)(b * TT + q0 + n) * HH + quad * 8;
    short8 aq0 = *(const short8*)(qr);
    short8 aq1 = *(const short8*)(qr + 32);

    f32x4 oc[4];
#pragma unroll
    for (int d = 0; d < 4; ++d) oc[d] = (f32x4){0.f, 0.f, 0.f, 0.f};
    float l_[4] = {0.f, 0.f, 0.f, 0.f};

    const int nkt = (q0 >> 6) + 1;

    for (int kt = wave; kt < nkt; kt += 4) {
        const int j0 = kt * 64;

        // ---- batched K fragment loads ----
        short8 bk0[4], bk1[4];
#pragma unroll
        for (int s = 0; s < 4; ++s) {
            const unsigned short* kr = kb + (size_t)(b * TT + j0 + s * 16 + n) * HH + quad * 8;
            bk0[s] = *(const short8*)(kr);
            bk1[s] = *(const short8*)(kr + 32);
        }

        // ---- V fragment loads issued NOW; consumed after exp/LDS phase ----
        short8 bv0[4], bv1[4];
#pragma unroll
        for (int d = 0; d < 4; ++d) {
            const unsigned short* vr = vT + (size_t)(b * HH + d * 16 + n) * TT + j0 + quad * 8;
            bv0[d] = *(const short8*)(vr);
            bv1[d] = *(const short8*)(vr + 32);
        }

        // ---- scores (base-2 logits; q pre-scaled) ----
        f32x4 sc[4];
#pragma unroll
        for (int s = 0; s < 4; ++s) sc[s] = (f32x4){0.f, 0.f, 0.f, 0.f};
        __builtin_amdgcn_s_setprio(1);
#pragma unroll
        for (int s = 0; s < 4; ++s) {
            sc[s] = __builtin_amdgcn_mfma_f32_16x16x32_bf16(aq0, bk0[s], sc[s], 0, 0, 0);
            sc[s] = __builtin_amdgcn_mfma_f32_16x16x32_bf16(aq1, bk1[s], sc[s], 0, 0, 0);
        }
        __builtin_amdgcn_s_setprio(0);

        // ---- p = exp2(sc), masked only on the (single) diagonal tile ----
        float p[4][4]; // [s][r]
        if (j0 + 63 <= q0) { // full tile (wave-uniform)
#pragma unroll
            for (int s = 0; s < 4; ++s)
#pragma unroll
                for (int r = 0; r < 4; ++r) {
                    float pe = exp2f(sc[s][r]);
                    p[s][r] = pe;
                    l_[r] += pe;
                }
        } else { // diagonal tile
#pragma unroll
            for (int r = 0; r < 4; ++r) {
                const int qrow = q0 + quad * 4 + r;
#pragma unroll
                for (int s = 0; s < 4; ++s) {
                    int krow = j0 + s * 16 + n;
                    float pe = (krow <= qrow) ? exp2f(sc[s][r]) : 0.f;
                    p[s][r] = pe;
                    l_[r] += pe;
                }
            }
        }

        // ---- P: C-layout -> wave-private LDS -> A-layout (proven R9/R10) ----
#pragma unroll
        for (int s = 0; s < 4; ++s) {
            unsigned int u01 = pkbf2(p[s][0], p[s][1]);
            unsigned int u23 = pkbf2(p[s][2], p[s][3]);
            Ps[wave][quad * 4 + 0][s * 16 + n] = (unsigned short)u01;
            Ps[wave][quad * 4 + 1][s * 16 + n] = (unsigned short)(u01 >> 16);
            Ps[wave][quad * 4 + 2][s * 16 + n] = (unsigned short)u23;
            Ps[wave][quad * 4 + 3][s * 16 + n] = (unsigned short)(u23 >> 16);
        }
        __asm__ volatile("s_waitcnt lgkmcnt(0)" ::: "memory");
        short8 ap0 = *(const short8*)&Ps[wave][n][quad * 8];
        short8 ap1 = *(const short8*)&Ps[wave][n][32 + quad * 8];

        // ---- O += P @ V (V already in registers) ----
        __builtin_amdgcn_s_setprio(1);
#pragma unroll
        for (int d = 0; d < 4; ++d) {
            oc[d] = __builtin_amdgcn_mfma_f32_16x16x32_bf16(ap0, bv0[d], oc[d], 0, 0, 0);
            oc[d] = __builtin_amdgcn_mfma_f32_16x16x32_bf16(ap1, bv1[d], oc[d], 0, 0, 0);
        }
        __builtin_amdgcn_s_setprio(0);
    }

    // ---- deferred l reduction across the 16 lanes sharing a row set ----
#pragma unroll
    for (int off = 1; off < 16; off <<= 1)
#pragma unroll
        for (int r = 0; r < 4; ++r)
            l_[r] += __shfl_xor(l_[r], off);

    // ---- cross-wave sum-merge ----
#pragma unroll
    for (int r = 0; r < 4; ++r) Lb[wave][lane][r] = l_[r];
#pragma unroll
    for (int d = 0; d < 4; ++d)
#pragma unroll
        for (int r = 0; r < 4; ++r)
            Ob[wave][lane][d * 4 + r] = oc[d][r];
    __syncthreads();

    if (wave == 0) {
#pragma unroll
        for (int r = 0; r < 4; ++r) {
            float ls = Lb[0][lane][r] + Lb[1][lane][r] + Lb[2][lane][r] + Lb[3][lane][r];
            const float inv = 1.f / ls;
#pragma unroll
            for (int d = 0; d < 4; ++d) {
                float o = Ob[0][lane][d * 4 + r] + Ob[1][lane][d * 4 + r] +
                          Ob[2][lane][d * 4 + r] + Ob[3][lane][d * 4 + r];
                out[(size_t)(b * TT + q0 + quad * 4 + r) * HH + d * 16 + n] = o * inv;
            }
        }
    }
}

// ---------------------------------------------------------------------------
extern "C" void kernel_launch(void* const* d_in, const int* in_sizes, int n_in,
                              void* d_out, int out_size, void* d_ws, size_t ws_size,
                              hipStream_t stream) {
    const float* x  = (const float*)d_in[0];
    const float* Wq = (const float*)d_in[1];
    const float* Wk = (const float*)d_in[2];
    const float* Wv = (const float*)d_in[3];
    float* out = (float*)d_out;

    char* ws = (char*)d_ws;
    unsigned short* Wb = (unsigned short*)(ws);              // 384 KB
    unsigned short* qb = (unsigned short*)(ws + (1u << 20)); // 1 MB
    unsigned short* kb = (unsigned short*)(ws + (2u << 20)); // 1 MB
    unsigned short* vT = (unsigned short*)(ws + (3u << 20)); // 1 MB

    prep_wb<<<96, 256, 0, stream>>>(Wq, Wk, Wv, Wb);
    qkv_mfma<<<256, 512, 0, stream>>>(x, Wb, out, qb, kb, vT);
    attn_mfma<<<dim3(128, 4), 256, 0, stream>>>(out, qb, kb, vT);
}